// Round 7
// baseline (237.271 us; speedup 1.0000x reference)
//
#include <hip/hip_runtime.h>
#include <hip/hip_bf16.h>

using bf16 = __hip_bfloat16;
typedef __attribute__((ext_vector_type(8))) short s16x8;
typedef __attribute__((ext_vector_type(4))) float f32x4;
typedef unsigned int u32;

__device__ __forceinline__ float b2f(short u) {
    union { float f; u32 i; } x; x.i = ((u32)(unsigned short)u) << 16; return x.f;
}
__device__ __forceinline__ short f2b(float f) {
    bf16 h = (bf16)f; return *(short*)&h;
}

// ---- convert fp32 -> bf16 (13 tensors: q,k,v + 10 weights) ----
struct CvtArgs { const float* src[13]; bf16* dst[13]; int n[13]; int bb[14]; };
__global__ __launch_bounds__(256)
void convert_kernel(CvtArgs a) {
    const int blk = blockIdx.x;
    int s = 0;
    while (s < 12 && blk >= a.bb[s + 1]) ++s;
    const int base = (blk - a.bb[s]) * 1024 + threadIdx.x * 4;
    if (base >= a.n[s]) return;            // all n % 4 == 0
    float4 v = *(const float4*)(a.src[s] + base);
    ushort4 o;
    o.x = (unsigned short)f2b(v.x); o.y = (unsigned short)f2b(v.y);
    o.z = (unsigned short)f2b(v.z); o.w = (unsigned short)f2b(v.w);
    *(ushort4*)(a.dst[s] + base) = o;
}

// ---- proj GEMM core: 128x64 tile, BK=32, reg-pipelined, bf16 A ----
// C[M,N] = A[M,K] @ W[N,K]^T + bias. 256 thr = 4 waves 2x2; wave owns 64x32.
template<bool OUT_F32>
__device__ __forceinline__ void gemm_128x64(
    const bf16* __restrict__ A, const bf16* __restrict__ W,
    const bf16* __restrict__ bias, void* __restrict__ out,
    int m0, int n0, int N, int K, bf16* lA, bf16* lB) {
    const int tid = threadIdx.x;
    const int wave = tid >> 6, lane = tid & 63;
    const int wr = wave >> 1, wc = wave & 1;
    const int quad = lane >> 4, lm = lane & 15;
    uint4 ra[2], rb;
    auto loadA = [&](int k0) {
#pragma unroll
        for (int q = 0; q < 2; ++q) {
            const int sl = q * 256 + tid;
            ra[q] = *(const uint4*)(A + (size_t)(m0 + (sl >> 2)) * K + k0 + (sl & 3) * 8);
        }
    };
    auto loadB = [&](int k0) {
        rb = *(const uint4*)(W + (size_t)(n0 + (tid >> 2)) * K + k0 + (tid & 3) * 8);
    };
    f32x4 acc[4][2] = {};
    loadA(0); loadB(0);
    for (int k0 = 0; k0 < K; k0 += 32) {
#pragma unroll
        for (int q = 0; q < 2; ++q) *(uint4*)(lA + (q * 256 + tid) * 8) = ra[q];
        *(uint4*)(lB + tid * 8) = rb;
        __syncthreads();
        if (k0 + 32 < K) { loadA(k0 + 32); loadB(k0 + 32); }   // overlaps MFMA
        s16x8 af[4], bf_[2];
#pragma unroll
        for (int i = 0; i < 4; ++i)
            af[i] = *(const s16x8*)&lA[(wr * 64 + i * 16 + lm) * 32 + quad * 8];
#pragma unroll
        for (int j = 0; j < 2; ++j)
            bf_[j] = *(const s16x8*)&lB[(wc * 32 + j * 16 + lm) * 32 + quad * 8];
#pragma unroll
        for (int i = 0; i < 4; ++i)
#pragma unroll
            for (int j = 0; j < 2; ++j)
                acc[i][j] = __builtin_amdgcn_mfma_f32_16x16x32_bf16(af[i], bf_[j], acc[i][j], 0, 0, 0);
        __syncthreads();
    }
#pragma unroll
    for (int i = 0; i < 4; ++i) {
        const int rbase = m0 + wr * 64 + i * 16 + quad * 4;
#pragma unroll
        for (int j = 0; j < 2; ++j) {
            const int col = n0 + wc * 32 + j * 16 + lm;
            const float bv = (float)bias[col];
#pragma unroll
            for (int r = 0; r < 4; ++r) {
                float v = acc[i][j][r] + bv;
                size_t off = (size_t)(rbase + r) * N + col;
                if (OUT_F32) ((float*)out)[off] = v;
                else         ((bf16*)out)[off] = (bf16)v;
            }
        }
    }
}

// ---- fused Q/K/V projection: 768 blocks (3/CU), XCD-swizzled ----
__global__ __launch_bounds__(256)
void proj_kernel(const bf16* __restrict__ qc, const bf16* __restrict__ kc,
                 const bf16* __restrict__ vc,
                 const bf16* __restrict__ Qkc, const bf16* __restrict__ Kkc,
                 const bf16* __restrict__ Vkc,
                 const bf16* __restrict__ Qbc, const bf16* __restrict__ Kbc,
                 const bf16* __restrict__ Vbc,
                 float* __restrict__ qp, float* __restrict__ kp,
                 bf16* __restrict__ vp) {
    __shared__ __align__(16) bf16 lA[128 * 32];
    __shared__ __align__(16) bf16 lB[64 * 32];
    const int L = blockIdx.x, xcd = L & 7, i = L >> 3;
    const int m0 = (xcd * 2 + i / 48) * 128;
    const int nid = i % 48;
    if (nid < 10)
        gemm_128x64<true >(qc, Qkc, Qbc, qp, m0, nid * 64, 640, 640, lA, lB);
    else if (nid < 20)
        gemm_128x64<true >(kc, Kkc, Kbc, kp, m0, (nid - 10) * 64, 640, 640, lA, lB);
    else
        gemm_128x64<false>(vc, Vkc, Vbc, vp, m0, (nid - 20) * 64, 1792, 640, lA, lB);
}

// ---- collapse GEMM: 64x64 tile, BK=64 (padded LDS stride 72), 320 blocks ----
__global__ __launch_bounds__(256)
void collapse_kernel(const bf16* __restrict__ atn, const bf16* __restrict__ Ckc,
                     const bf16* __restrict__ Cbc, float* __restrict__ out) {
    __shared__ __align__(16) bf16 lA[64 * 72];
    __shared__ __align__(16) bf16 lB[64 * 72];
    const int L = blockIdx.x, xcd = L & 7, i = L >> 3;
    const int m0 = (xcd * 4 + i / 10) * 64;
    const int n0 = (i % 10) * 64;
    const int K = 1792, N = 640;
    const int tid = threadIdx.x;
    const int wave = tid >> 6, lane = tid & 63;
    const int wr = wave >> 1, wc = wave & 1;
    const int quad = lane >> 4, lm = lane & 15;
    uint4 ra[2], rb[2];
    auto loadAB = [&](int k0) {
#pragma unroll
        for (int q = 0; q < 2; ++q) {
            const int sl = q * 256 + tid, row = sl >> 3, col8 = (sl & 7) * 8;
            ra[q] = *(const uint4*)(atn + (size_t)(m0 + row) * K + k0 + col8);
            rb[q] = *(const uint4*)(Ckc + (size_t)(n0 + row) * K + k0 + col8);
        }
    };
    f32x4 acc[2][2] = {};
    loadAB(0);
    for (int k0 = 0; k0 < K; k0 += 64) {
#pragma unroll
        for (int q = 0; q < 2; ++q) {
            const int sl = q * 256 + tid, row = sl >> 3, col8 = (sl & 7) * 8;
            *(uint4*)(lA + row * 72 + col8) = ra[q];
            *(uint4*)(lB + row * 72 + col8) = rb[q];
        }
        __syncthreads();
        if (k0 + 64 < K) loadAB(k0 + 64);     // overlaps MFMA
#pragma unroll
        for (int kk = 0; kk < 2; ++kk) {
            s16x8 af[2], bf_[2];
#pragma unroll
            for (int i2 = 0; i2 < 2; ++i2)
                af[i2] = *(const s16x8*)&lA[(wr * 32 + i2 * 16 + lm) * 72 + kk * 32 + quad * 8];
#pragma unroll
            for (int j = 0; j < 2; ++j)
                bf_[j] = *(const s16x8*)&lB[(wc * 32 + j * 16 + lm) * 72 + kk * 32 + quad * 8];
#pragma unroll
            for (int i2 = 0; i2 < 2; ++i2)
#pragma unroll
                for (int j = 0; j < 2; ++j)
                    acc[i2][j] = __builtin_amdgcn_mfma_f32_16x16x32_bf16(af[i2], bf_[j], acc[i2][j], 0, 0, 0);
        }
        __syncthreads();
    }
#pragma unroll
    for (int i2 = 0; i2 < 2; ++i2) {
        const int rbase = m0 + wr * 32 + i2 * 16 + quad * 4;
#pragma unroll
        for (int j = 0; j < 2; ++j) {
            const int col = n0 + wc * 32 + j * 16 + lm;
            const float bv = (float)Cbc[col];
#pragma unroll
            for (int r = 0; r < 4; ++r)
                out[(size_t)(rbase + r) * N + col] = acc[i2][j][r] + bv;
        }
    }
}

// ---- attention core: one block per position, XCD-swizzled (R6 version) ----
__global__ __launch_bounds__(256)
void attn_v4(const float* __restrict__ qp, const float* __restrict__ kp,
             const bf16* __restrict__ vp,
             const bf16* __restrict__ Kbc, const bf16* __restrict__ Vbc,
             const bf16* __restrict__ Skc, const bf16* __restrict__ Sbc,
             bf16* __restrict__ atn) {
    const int pos = ((blockIdx.x & 7) << 8) | (blockIdx.x >> 3);  // XCD-contiguous
    const int b = pos >> 10, l = pos & 1023;
    const int t = threadIdx.x;
    __shared__ float qs[640];
    __shared__ float sc5[5 * 32];
    __shared__ float sc14[14 * 32];
    __shared__ float w14T[32 * 14];   // transposed: [tap][head]

    if (t < 160) ((float4*)qs)[t] = ((const float4*)(qp + (size_t)pos * 640))[t];
    __syncthreads();

    // Phase A: score[s][j] = q[s].kwin[s][j]; 8 lanes/dot, stride-32 interleave
    {
        const int j = t >> 3, p = t & 7;
#pragma unroll
        for (int s = 0; s < 5; ++s) {
            const int dil = (s < 2) ? 1 : (1 << (s - 1));
            const int pl = (31 * dil) >> 1;
            const int row = l + j * dil - pl;
            const float* q = qs + s * 128 + p * 4;
            float acc = 0.f;
            if (row >= 0 && row < 1024) {
                const float* kr = kp + (size_t)((b << 10) | row) * 640 + s * 128 + p * 4;
#pragma unroll
                for (int g = 0; g < 4; ++g) {
                    float4 kv = *(const float4*)(kr + g * 32);
                    float4 qv = *(const float4*)(q + g * 32);
                    acc += qv.x * kv.x + qv.y * kv.y + qv.z * kv.z + qv.w * kv.w;
                }
            } else {
                const bf16* kb = Kbc + s * 128 + p * 4;   // pad rows project the bias
#pragma unroll
                for (int g = 0; g < 4; ++g) {
                    float4 qv = *(const float4*)(q + g * 32);
                    acc += qv.x * (float)kb[g * 32] + qv.y * (float)kb[g * 32 + 1]
                         + qv.z * (float)kb[g * 32 + 2] + qv.w * (float)kb[g * 32 + 3];
                }
            }
            acc += __shfl_xor(acc, 1);
            acc += __shfl_xor(acc, 2);
            acc += __shfl_xor(acc, 4);
            if (p == 0) sc5[s * 32 + j] = acc;
        }
    }
    __syncthreads();

    // Phase B: supersample + positional resampling (448 outputs), vectorized Sk
    for (int idx = t; idx < 448; idx += 256) {
        const int h = idx >> 5;
        const int s = (h < 5) ? 0 : (h < 10) ? 1 : (h < 12) ? 2 : (h == 12) ? 3 : 4;
        const s16x8* sk = (const s16x8*)((const short*)Skc + idx * 32);
        const float* sc = sc5 + s * 32;
        float acc = b2f(((const short*)Sbc)[idx]);
#pragma unroll
        for (int g = 0; g < 4; ++g) {
            s16x8 kk = sk[g];
#pragma unroll
            for (int r = 0; r < 8; ++r) acc += sc[g * 8 + r] * b2f(kk[r]);
        }
        sc14[idx] = acc;
    }
    __syncthreads();

    // Phase C: softmax, 16 lanes/head (2 taps each), shuffle-reduce width 16
    if (t < 224) {
        const int h = t >> 4, u = t & 15;
        float s0 = sc14[h * 32 + u], s1 = sc14[h * 32 + u + 16];
        float mx = fmaxf(s0, s1);
#pragma unroll
        for (int m = 1; m < 16; m <<= 1) mx = fmaxf(mx, __shfl_xor(mx, m));
        float e0 = __expf(s0 - mx), e1 = __expf(s1 - mx);
        float sum = e0 + e1;
#pragma unroll
        for (int m = 1; m < 16; m <<= 1) sum += __shfl_xor(sum, m);
        float inv = 1.f / sum;
        w14T[u * 14 + h] = e0 * inv;
        w14T[(u + 16) * 14 + h] = e1 * inv;
    }
    __syncthreads();

    // Phase D: attn[h][d8] = sum_j w[j][h] * vwin[h][j][d8]
    if (t < 224) {
        const int h = t >> 4, d8 = (t & 15) * 8;
        const int dil = (h < 10) ? 1 : (h < 12) ? 2 : (h == 12) ? 4 : 8;
        const int pl = (31 * dil) >> 1;
        const int col = h * 128 + d8;
        float acc[8] = {};
#pragma unroll
        for (int j = 0; j < 32; ++j) {
            const int row = l + j * dil - pl;
            const short* src = (row >= 0 && row < 1024)
                ? (const short*)vp + (size_t)((b << 10) | row) * 1792 + col
                : (const short*)Vbc + col;     // pad rows project the bias
            s16x8 v8 = *(const s16x8*)src;
            const float w = w14T[j * 14 + h];
#pragma unroll
            for (int r = 0; r < 8; ++r) acc[r] += w * b2f(v8[r]);
        }
        union { uint4 u; short h16[8]; } o;
#pragma unroll
        for (int r = 0; r < 8; ++r) o.h16[r] = f2b(acc[r]);
        *(uint4*)((short*)atn + (size_t)pos * 1792 + col) = o.u;
    }
}

extern "C" void kernel_launch(void* const* d_in, const int* in_sizes, int n_in,
                              void* d_out, int out_size, void* d_ws, size_t ws_size,
                              hipStream_t stream) {
    const int M = 2048;
    char* w = (char*)d_ws;
    size_t off = 0;
    auto alloc = [&](size_t bytes) -> char* {
        off = (off + 255) & ~(size_t)255;
        char* p = w + off; off += bytes; return p;
    };
    bf16* qc  = (bf16*)alloc(1310720 * 2);
    bf16* kc  = (bf16*)alloc(1310720 * 2);
    bf16* vc  = (bf16*)alloc(1310720 * 2);
    bf16* Qkc = (bf16*)alloc(409600 * 2);
    bf16* Qbc = (bf16*)alloc(640 * 2);
    bf16* Kkc = (bf16*)alloc(409600 * 2);
    bf16* Kbc = (bf16*)alloc(640 * 2);
    bf16* Vkc = (bf16*)alloc(1146880 * 2);
    bf16* Vbc = (bf16*)alloc(1792 * 2);
    bf16* Skc = (bf16*)alloc(14336 * 2);
    bf16* Sbc = (bf16*)alloc(448 * 2);
    bf16* Ckc = (bf16*)alloc(1146880 * 2);
    bf16* Cbc = (bf16*)alloc(640 * 2);
    float* qp = (float*)alloc((size_t)M * 640 * 4);
    float* kp = (float*)alloc((size_t)M * 640 * 4);
    bf16*  vp = (bf16*)alloc((size_t)M * 1792 * 2);
    bf16*  atn = (bf16*)alloc((size_t)M * 1792 * 2);

    CvtArgs ca;
    bf16* dsts[13] = {qc, kc, vc, Qkc, Qbc, Kkc, Kbc, Vkc, Vbc, Skc, Sbc, Ckc, Cbc};
    const int ns[13] = {1310720, 1310720, 1310720, 409600, 640, 409600, 640,
                        1146880, 1792, 14336, 448, 1146880, 640};
    int cum = 0;
    for (int i = 0; i < 13; ++i) {
        ca.src[i] = (const float*)d_in[i];
        ca.dst[i] = dsts[i];
        ca.n[i] = ns[i];
        ca.bb[i] = cum;
        cum += (ns[i] + 1023) / 1024;
    }
    ca.bb[13] = cum;

    dim3 blk(256);
    convert_kernel<<<dim3(cum), blk, 0, stream>>>(ca);
    proj_kernel<<<dim3(768), blk, 0, stream>>>(qc, kc, vc, Qkc, Kkc, Vkc,
                                               Qbc, Kbc, Vbc, qp, kp, vp);
    attn_v4<<<dim3(2048), blk, 0, stream>>>(qp, kp, vp, Kbc, Vbc, Skc, Sbc, atn);
    collapse_kernel<<<dim3(320), blk, 0, stream>>>(atn, Ckc, Cbc, (float*)d_out);
}

// Round 8
// 194.600 us; speedup vs baseline: 1.2193x; 1.2193x over previous
//
#include <hip/hip_runtime.h>
#include <hip/hip_bf16.h>

using bf16 = __hip_bfloat16;
typedef __attribute__((ext_vector_type(8))) short s16x8;
typedef __attribute__((ext_vector_type(4))) float f32x4;
typedef unsigned int u32;

__device__ __forceinline__ float b2f(short u) {
    union { float f; u32 i; } x; x.i = ((u32)(unsigned short)u) << 16; return x.f;
}
__device__ __forceinline__ short f2b(float f) {
    bf16 h = (bf16)f; return *(short*)&h;
}

// ---- convert fp32 -> bf16 (13 tensors: q,k,v + 10 weights) ----
struct CvtArgs { const float* src[13]; bf16* dst[13]; int n[13]; int bb[14]; };
__global__ __launch_bounds__(256)
void convert_kernel(CvtArgs a) {
    const int blk = blockIdx.x;
    int s = 0;
    while (s < 12 && blk >= a.bb[s + 1]) ++s;
    const int base = (blk - a.bb[s]) * 1024 + threadIdx.x * 4;
    if (base >= a.n[s]) return;            // all n % 4 == 0
    float4 v = *(const float4*)(a.src[s] + base);
    ushort4 o;
    o.x = (unsigned short)f2b(v.x); o.y = (unsigned short)f2b(v.y);
    o.z = (unsigned short)f2b(v.z); o.w = (unsigned short)f2b(v.w);
    *(ushort4*)(a.dst[s] + base) = o;
}

// ---- proj GEMM core: 128x64 tile, BK=32, reg-pipelined, bf16 A (R7, kept) ----
template<bool OUT_F32>
__device__ __forceinline__ void gemm_128x64(
    const bf16* __restrict__ A, const bf16* __restrict__ W,
    const bf16* __restrict__ bias, void* __restrict__ out,
    int m0, int n0, int N, int K, bf16* lA, bf16* lB) {
    const int tid = threadIdx.x;
    const int wave = tid >> 6, lane = tid & 63;
    const int wr = wave >> 1, wc = wave & 1;
    const int quad = lane >> 4, lm = lane & 15;
    uint4 ra[2], rb;
    auto loadA = [&](int k0) {
#pragma unroll
        for (int q = 0; q < 2; ++q) {
            const int sl = q * 256 + tid;
            ra[q] = *(const uint4*)(A + (size_t)(m0 + (sl >> 2)) * K + k0 + (sl & 3) * 8);
        }
    };
    auto loadB = [&](int k0) {
        rb = *(const uint4*)(W + (size_t)(n0 + (tid >> 2)) * K + k0 + (tid & 3) * 8);
    };
    f32x4 acc[4][2] = {};
    loadA(0); loadB(0);
    for (int k0 = 0; k0 < K; k0 += 32) {
#pragma unroll
        for (int q = 0; q < 2; ++q) *(uint4*)(lA + (q * 256 + tid) * 8) = ra[q];
        *(uint4*)(lB + tid * 8) = rb;
        __syncthreads();
        if (k0 + 32 < K) { loadA(k0 + 32); loadB(k0 + 32); }   // overlaps MFMA
        s16x8 af[4], bf_[2];
#pragma unroll
        for (int i = 0; i < 4; ++i)
            af[i] = *(const s16x8*)&lA[(wr * 64 + i * 16 + lm) * 32 + quad * 8];
#pragma unroll
        for (int j = 0; j < 2; ++j)
            bf_[j] = *(const s16x8*)&lB[(wc * 32 + j * 16 + lm) * 32 + quad * 8];
#pragma unroll
        for (int i = 0; i < 4; ++i)
#pragma unroll
            for (int j = 0; j < 2; ++j)
                acc[i][j] = __builtin_amdgcn_mfma_f32_16x16x32_bf16(af[i], bf_[j], acc[i][j], 0, 0, 0);
        __syncthreads();
    }
#pragma unroll
    for (int i = 0; i < 4; ++i) {
        const int rbase = m0 + wr * 64 + i * 16 + quad * 4;
#pragma unroll
        for (int j = 0; j < 2; ++j) {
            const int col = n0 + wc * 32 + j * 16 + lm;
            const float bv = (float)bias[col];
#pragma unroll
            for (int r = 0; r < 4; ++r) {
                float v = acc[i][j][r] + bv;
                size_t off = (size_t)(rbase + r) * N + col;
                if (OUT_F32) ((float*)out)[off] = v;
                else         ((bf16*)out)[off] = (bf16)v;
            }
        }
    }
}

// ---- fused Q/K/V projection: 768 blocks (3/CU), XCD-swizzled ----
__global__ __launch_bounds__(256)
void proj_kernel(const bf16* __restrict__ qc, const bf16* __restrict__ kc,
                 const bf16* __restrict__ vc,
                 const bf16* __restrict__ Qkc, const bf16* __restrict__ Kkc,
                 const bf16* __restrict__ Vkc,
                 const bf16* __restrict__ Qbc, const bf16* __restrict__ Kbc,
                 const bf16* __restrict__ Vbc,
                 float* __restrict__ qp, float* __restrict__ kp,
                 bf16* __restrict__ vp) {
    __shared__ __align__(16) bf16 lA[128 * 32];
    __shared__ __align__(16) bf16 lB[64 * 32];
    const int L = blockIdx.x, xcd = L & 7, i = L >> 3;
    const int m0 = (xcd * 2 + i / 48) * 128;
    const int nid = i % 48;
    if (nid < 10)
        gemm_128x64<true >(qc, Qkc, Qbc, qp, m0, nid * 64, 640, 640, lA, lB);
    else if (nid < 20)
        gemm_128x64<true >(kc, Kkc, Kbc, kp, m0, (nid - 10) * 64, 640, 640, lA, lB);
    else
        gemm_128x64<false>(vc, Vkc, Vbc, vp, m0, (nid - 20) * 64, 1792, 640, lA, lB);
}

// ---- collapse GEMM: REVERTED to R6 structure (BK=32, reg-pipelined 64x64) ----
__global__ __launch_bounds__(256)
void collapse_kernel(const bf16* __restrict__ atn, const bf16* __restrict__ Ckc,
                     const bf16* __restrict__ Cbc, float* __restrict__ out) {
    __shared__ __align__(16) bf16 lA[64 * 32];
    __shared__ __align__(16) bf16 lB[64 * 32];
    const int L = blockIdx.x, xcd = L & 7, i = L >> 3;
    const int m0 = (xcd * 4 + i / 10) * 64;
    const int n0 = (i % 10) * 64;
    const int K = 1792, N = 640;
    const int tid = threadIdx.x;
    const int wave = tid >> 6, lane = tid & 63;
    const int wr = wave >> 1, wc = wave & 1;
    const int quad = lane >> 4, lm = lane & 15;
    uint4 ra, rb;
    auto loadA = [&](int k0) {
        ra = *(const uint4*)(atn + (size_t)(m0 + (tid >> 2)) * K + k0 + (tid & 3) * 8);
    };
    auto loadB = [&](int k0) {
        rb = *(const uint4*)(Ckc + (size_t)(n0 + (tid >> 2)) * K + k0 + (tid & 3) * 8);
    };
    f32x4 acc[2][2] = {};
    loadA(0); loadB(0);
    for (int k0 = 0; k0 < K; k0 += 32) {
        *(uint4*)(lA + tid * 8) = ra;
        *(uint4*)(lB + tid * 8) = rb;
        __syncthreads();
        if (k0 + 32 < K) { loadA(k0 + 32); loadB(k0 + 32); }   // overlaps MFMA
        s16x8 af[2], bf_[2];
#pragma unroll
        for (int i2 = 0; i2 < 2; ++i2)
            af[i2] = *(const s16x8*)&lA[(wr * 32 + i2 * 16 + lm) * 32 + quad * 8];
#pragma unroll
        for (int j = 0; j < 2; ++j)
            bf_[j] = *(const s16x8*)&lB[(wc * 32 + j * 16 + lm) * 32 + quad * 8];
#pragma unroll
        for (int i2 = 0; i2 < 2; ++i2)
#pragma unroll
            for (int j = 0; j < 2; ++j)
                acc[i2][j] = __builtin_amdgcn_mfma_f32_16x16x32_bf16(af[i2], bf_[j], acc[i2][j], 0, 0, 0);
        __syncthreads();
    }
#pragma unroll
    for (int i2 = 0; i2 < 2; ++i2) {
        const int rbase = m0 + wr * 32 + i2 * 16 + quad * 4;
#pragma unroll
        for (int j = 0; j < 2; ++j) {
            const int col = n0 + wc * 32 + j * 16 + lm;
            const float bv = (float)Cbc[col];
#pragma unroll
            for (int r = 0; r < 4; ++r)
                out[(size_t)(rbase + r) * N + col] = acc[i2][j][r] + bv;
        }
    }
}

// ---- attention core: one block per position, XCD-swizzled ----
__global__ __launch_bounds__(256)
void attn_v4(const float* __restrict__ qp, const float* __restrict__ kp,
             const bf16* __restrict__ vp,
             const bf16* __restrict__ Kbc, const bf16* __restrict__ Vbc,
             const bf16* __restrict__ Skc, const bf16* __restrict__ Sbc,
             bf16* __restrict__ atn) {
    const int pos = ((blockIdx.x & 7) << 8) | (blockIdx.x >> 3);  // XCD-contiguous
    const int b = pos >> 10, l = pos & 1023;
    const int t = threadIdx.x;
    __shared__ float qs[640];
    __shared__ float sc5[5 * 32];
    __shared__ float sc14[14 * 32];
    __shared__ float w14T[32 * 14];   // transposed: [tap][head]

    if (t < 160) ((float4*)qs)[t] = ((const float4*)(qp + (size_t)pos * 640))[t];
    __syncthreads();

    // Phase A: score[s][j] = q[s].kwin[s][j]; 8 lanes/dot, stride-32 interleave
    {
        const int j = t >> 3, p = t & 7;
#pragma unroll
        for (int s = 0; s < 5; ++s) {
            const int dil = (s < 2) ? 1 : (1 << (s - 1));
            const int pl = (31 * dil) >> 1;
            const int row = l + j * dil - pl;
            const float* q = qs + s * 128 + p * 4;
            float acc = 0.f;
            if (row >= 0 && row < 1024) {
                const float* kr = kp + (size_t)((b << 10) | row) * 640 + s * 128 + p * 4;
#pragma unroll
                for (int g = 0; g < 4; ++g) {
                    float4 kv = *(const float4*)(kr + g * 32);
                    float4 qv = *(const float4*)(q + g * 32);
                    acc += qv.x * kv.x + qv.y * kv.y + qv.z * kv.z + qv.w * kv.w;
                }
            } else {
                const bf16* kb = Kbc + s * 128 + p * 4;   // pad rows project the bias
#pragma unroll
                for (int g = 0; g < 4; ++g) {
                    float4 qv = *(const float4*)(q + g * 32);
                    acc += qv.x * (float)kb[g * 32] + qv.y * (float)kb[g * 32 + 1]
                         + qv.z * (float)kb[g * 32 + 2] + qv.w * (float)kb[g * 32 + 3];
                }
            }
            acc += __shfl_xor(acc, 1);
            acc += __shfl_xor(acc, 2);
            acc += __shfl_xor(acc, 4);
            if (p == 0) sc5[s * 32 + j] = acc;
        }
    }
    __syncthreads();

    // Phase B: supersample + positional resampling (448 outputs), vectorized Sk
    for (int idx = t; idx < 448; idx += 256) {
        const int h = idx >> 5;
        const int s = (h < 5) ? 0 : (h < 10) ? 1 : (h < 12) ? 2 : (h == 12) ? 3 : 4;
        const s16x8* sk = (const s16x8*)((const short*)Skc + idx * 32);
        const float* sc = sc5 + s * 32;
        float acc = b2f(((const short*)Sbc)[idx]);
#pragma unroll
        for (int g = 0; g < 4; ++g) {
            s16x8 kk = sk[g];
#pragma unroll
            for (int r = 0; r < 8; ++r) acc += sc[g * 8 + r] * b2f(kk[r]);
        }
        sc14[idx] = acc;
    }
    __syncthreads();

    // Phase C: softmax, 16 lanes/head (2 taps each), shuffle-reduce width 16
    if (t < 224) {
        const int h = t >> 4, u = t & 15;
        float s0 = sc14[h * 32 + u], s1 = sc14[h * 32 + u + 16];
        float mx = fmaxf(s0, s1);
#pragma unroll
        for (int m = 1; m < 16; m <<= 1) mx = fmaxf(mx, __shfl_xor(mx, m));
        float e0 = __expf(s0 - mx), e1 = __expf(s1 - mx);
        float sum = e0 + e1;
#pragma unroll
        for (int m = 1; m < 16; m <<= 1) sum += __shfl_xor(sum, m);
        float inv = 1.f / sum;
        w14T[u * 14 + h] = e0 * inv;
        w14T[(u + 16) * 14 + h] = e1 * inv;
    }
    __syncthreads();

    // Phase D: attn[h][d8] = sum_j w[j][h] * vwin[h][j][d8]
    if (t < 224) {
        const int h = t >> 4, d8 = (t & 15) * 8;
        const int dil = (h < 10) ? 1 : (h < 12) ? 2 : (h == 12) ? 4 : 8;
        const int pl = (31 * dil) >> 1;
        const int col = h * 128 + d8;
        float acc[8] = {};
#pragma unroll
        for (int j = 0; j < 32; ++j) {
            const int row = l + j * dil - pl;
            const short* src = (row >= 0 && row < 1024)
                ? (const short*)vp + (size_t)((b << 10) | row) * 1792 + col
                : (const short*)Vbc + col;     // pad rows project the bias
            s16x8 v8 = *(const s16x8*)src;
            const float w = w14T[j * 14 + h];
#pragma unroll
            for (int r = 0; r < 8; ++r) acc[r] += w * b2f(v8[r]);
        }
        union { uint4 u; short h16[8]; } o;
#pragma unroll
        for (int r = 0; r < 8; ++r) o.h16[r] = f2b(acc[r]);
        *(uint4*)((short*)atn + (size_t)pos * 1792 + col) = o.u;
    }
}

extern "C" void kernel_launch(void* const* d_in, const int* in_sizes, int n_in,
                              void* d_out, int out_size, void* d_ws, size_t ws_size,
                              hipStream_t stream) {
    const int M = 2048;
    char* w = (char*)d_ws;
    size_t off = 0;
    auto alloc = [&](size_t bytes) -> char* {
        off = (off + 255) & ~(size_t)255;
        char* p = w + off; off += bytes; return p;
    };
    bf16* qc  = (bf16*)alloc(1310720 * 2);
    bf16* kc  = (bf16*)alloc(1310720 * 2);
    bf16* vc  = (bf16*)alloc(1310720 * 2);
    bf16* Qkc = (bf16*)alloc(409600 * 2);
    bf16* Qbc = (bf16*)alloc(640 * 2);
    bf16* Kkc = (bf16*)alloc(409600 * 2);
    bf16* Kbc = (bf16*)alloc(640 * 2);
    bf16* Vkc = (bf16*)alloc(1146880 * 2);
    bf16* Vbc = (bf16*)alloc(1792 * 2);
    bf16* Skc = (bf16*)alloc(14336 * 2);
    bf16* Sbc = (bf16*)alloc(448 * 2);
    bf16* Ckc = (bf16*)alloc(1146880 * 2);
    bf16* Cbc = (bf16*)alloc(640 * 2);
    float* qp = (float*)alloc((size_t)M * 640 * 4);
    float* kp = (float*)alloc((size_t)M * 640 * 4);
    bf16*  vp = (bf16*)alloc((size_t)M * 1792 * 2);
    bf16*  atn = (bf16*)alloc((size_t)M * 1792 * 2);

    CvtArgs ca;
    bf16* dsts[13] = {qc, kc, vc, Qkc, Qbc, Kkc, Kbc, Vkc, Vbc, Skc, Sbc, Ckc, Cbc};
    const int ns[13] = {1310720, 1310720, 1310720, 409600, 640, 409600, 640,
                        1146880, 1792, 14336, 448, 1146880, 640};
    int cum = 0;
    for (int i = 0; i < 13; ++i) {
        ca.src[i] = (const float*)d_in[i];
        ca.dst[i] = dsts[i];
        ca.n[i] = ns[i];
        ca.bb[i] = cum;
        cum += (ns[i] + 1023) / 1024;
    }
    ca.bb[13] = cum;

    dim3 blk(256);
    convert_kernel<<<dim3(cum), blk, 0, stream>>>(ca);
    proj_kernel<<<dim3(768), blk, 0, stream>>>(qc, kc, vc, Qkc, Kkc, Vkc,
                                               Qbc, Kbc, Vbc, qp, kp, vp);
    attn_v4<<<dim3(2048), blk, 0, stream>>>(qp, kp, vp, Kbc, Vbc, Skc, Sbc, atn);
    collapse_kernel<<<dim3(320), blk, 0, stream>>>(atn, Ckc, Cbc, (float*)d_out);
}

// Round 9
// 164.192 us; speedup vs baseline: 1.4451x; 1.1852x over previous
//
#include <hip/hip_runtime.h>
#include <hip/hip_bf16.h>

using bf16 = __hip_bfloat16;
typedef __attribute__((ext_vector_type(8))) short s16x8;
typedef __attribute__((ext_vector_type(4))) float f32x4;
typedef unsigned int u32;

__device__ __forceinline__ float b2f(short u) {
    union { float f; u32 i; } x; x.i = ((u32)(unsigned short)u) << 16; return x.f;
}
__device__ __forceinline__ short f2b(float f) {
    bf16 h = (bf16)f; return *(short*)&h;
}

// ---- convert weights fp32 -> bf16 (10 tensors; q/k/v stay fp32 and are
// converted in proj's staging path — reading pristine d_in is faster than
// reading freshly-written ws intermediates cross-XCD, per R5/R8 evidence) ----
struct CvtArgs { const float* src[10]; bf16* dst[10]; int n[10]; int bb[11]; };
__global__ __launch_bounds__(256)
void convert_kernel(CvtArgs a) {
    const int blk = blockIdx.x;
    int s = 0;
    while (s < 9 && blk >= a.bb[s + 1]) ++s;
    const int base = (blk - a.bb[s]) * 1024 + threadIdx.x * 4;
    if (base >= a.n[s]) return;            // all n % 4 == 0
    float4 v = *(const float4*)(a.src[s] + base);
    ushort4 o;
    o.x = (unsigned short)f2b(v.x); o.y = (unsigned short)f2b(v.y);
    o.z = (unsigned short)f2b(v.z); o.w = (unsigned short)f2b(v.w);
    *(ushort4*)(a.dst[s] + base) = o;
}

// ---- register-pipelined GEMM core (R6): C[M,N] = A[M,K] @ W[N,K]^T + bias ----
// 256 threads = 4 waves (2x2). Global->VGPR staging for tile k+1 issued after
// the barrier, overlapping ds_read+MFMA of tile k. A fp32 (convert-on-stage)
// or bf16; W bf16.
template<int BM, int BN, bool A_F32, bool OUT_F32>
__device__ __forceinline__ void gemm_pipe(
    const void* __restrict__ A, const bf16* __restrict__ W,
    const bf16* __restrict__ bias, void* __restrict__ out,
    int m0, int n0, int N, int K, bf16* lA, bf16* lB) {
    constexpr int WM = BM / 2, WN = BN / 2, FM = WM / 16, FN = WN / 16;
    constexpr int SA = BM / 64, SB = BN / 64;   // 16B reg slots per thread
    const int tid = threadIdx.x;
    const int wave = tid >> 6, lane = tid & 63;
    const int wr = wave >> 1, wc = wave & 1;
    const int quad = lane >> 4, lm = lane & 15;
    uint4 ra[SA], rb[SB];

    auto loadA = [&](int k0) {
#pragma unroll
        for (int q = 0; q < SA; ++q) {
            const int sl = q * 256 + tid, row = sl >> 2, col = (sl & 3) * 8;
            if (A_F32) {
                const float* g = (const float*)A + (size_t)(m0 + row) * K + k0 + col;
                float4 f0 = *(const float4*)g;
                float4 f1 = *(const float4*)(g + 4);
                union { uint4 u; short h[8]; } p;
                p.h[0] = f2b(f0.x); p.h[1] = f2b(f0.y); p.h[2] = f2b(f0.z); p.h[3] = f2b(f0.w);
                p.h[4] = f2b(f1.x); p.h[5] = f2b(f1.y); p.h[6] = f2b(f1.z); p.h[7] = f2b(f1.w);
                ra[q] = p.u;
            } else {
                ra[q] = *(const uint4*)((const bf16*)A + (size_t)(m0 + row) * K + k0 + col);
            }
        }
    };
    auto loadB = [&](int k0) {
#pragma unroll
        for (int q = 0; q < SB; ++q) {
            const int sl = q * 256 + tid, row = sl >> 2, col = (sl & 3) * 8;
            rb[q] = *(const uint4*)(W + (size_t)(n0 + row) * K + k0 + col);
        }
    };

    f32x4 acc[FM][FN] = {};
    loadA(0); loadB(0);
    for (int k0 = 0; k0 < K; k0 += 32) {
#pragma unroll
        for (int q = 0; q < SA; ++q) *(uint4*)(lA + (q * 256 + tid) * 8) = ra[q];
#pragma unroll
        for (int q = 0; q < SB; ++q) *(uint4*)(lB + (q * 256 + tid) * 8) = rb[q];
        __syncthreads();
        if (k0 + 32 < K) { loadA(k0 + 32); loadB(k0 + 32); }   // overlaps MFMA below
        s16x8 af[FM], bf_[FN];
#pragma unroll
        for (int i = 0; i < FM; ++i)
            af[i] = *(const s16x8*)&lA[(wr * WM + i * 16 + lm) * 32 + quad * 8];
#pragma unroll
        for (int j = 0; j < FN; ++j)
            bf_[j] = *(const s16x8*)&lB[(wc * WN + j * 16 + lm) * 32 + quad * 8];
#pragma unroll
        for (int i = 0; i < FM; ++i)
#pragma unroll
            for (int j = 0; j < FN; ++j)
                acc[i][j] = __builtin_amdgcn_mfma_f32_16x16x32_bf16(af[i], bf_[j], acc[i][j], 0, 0, 0);
        __syncthreads();
    }
#pragma unroll
    for (int i = 0; i < FM; ++i) {
        const int rbase = m0 + wr * WM + i * 16 + quad * 4;
#pragma unroll
        for (int j = 0; j < FN; ++j) {
            const int col = n0 + wc * WN + j * 16 + lm;
            const float bv = (float)bias[col];
#pragma unroll
            for (int r = 0; r < 4; ++r) {
                float v = acc[i][j][r] + bv;
                size_t off = (size_t)(rbase + r) * N + col;
                if (OUT_F32) ((float*)out)[off] = v;
                else         ((bf16*)out)[off] = (bf16)v;
            }
        }
    }
}

// ---- fused Q/K/V projection: 768 blocks (3/CU), 128x64 tiles, XCD-swizzled ----
__global__ __launch_bounds__(256)
void proj_kernel(const float* __restrict__ q, const float* __restrict__ k,
                 const float* __restrict__ v,
                 const bf16* __restrict__ Qkc, const bf16* __restrict__ Kkc,
                 const bf16* __restrict__ Vkc,
                 const bf16* __restrict__ Qbc, const bf16* __restrict__ Kbc,
                 const bf16* __restrict__ Vbc,
                 float* __restrict__ qp, float* __restrict__ kp,
                 bf16* __restrict__ vp) {
    __shared__ __align__(16) bf16 lA[128 * 32];
    __shared__ __align__(16) bf16 lB[64 * 32];
    const int L = blockIdx.x, xcd = L & 7, i = L >> 3;
    const int m0 = (xcd * 2 + i / 48) * 128;
    const int nid = i % 48;
    if (nid < 10)
        gemm_pipe<128, 64, true, true >(q, Qkc, Qbc, qp, m0, nid * 64, 640, 640, lA, lB);
    else if (nid < 20)
        gemm_pipe<128, 64, true, true >(k, Kkc, Kbc, kp, m0, (nid - 10) * 64, 640, 640, lA, lB);
    else
        gemm_pipe<128, 64, true, false>(v, Vkc, Vbc, vp, m0, (nid - 20) * 64, 1792, 640, lA, lB);
}

// ---- collapse GEMM: 320 blocks (1.25/CU) of 64x64, K=1792, XCD-swizzled ----
__global__ __launch_bounds__(256)
void collapse_kernel(const bf16* __restrict__ atn, const bf16* __restrict__ Ckc,
                     const bf16* __restrict__ Cbc, float* __restrict__ out) {
    __shared__ __align__(16) bf16 lA[64 * 32];
    __shared__ __align__(16) bf16 lB[64 * 32];
    const int L = blockIdx.x, xcd = L & 7, i = L >> 3;
    const int m0 = (xcd * 4 + i / 10) * 64;
    const int n0 = (i % 10) * 64;
    gemm_pipe<64, 64, false, true>(atn, Ckc, Cbc, out, m0, n0, 640, 1792, lA, lB);
}

// ---- attention core: one block per position, XCD-swizzled ----
__global__ __launch_bounds__(256)
void attn_v4(const float* __restrict__ qp, const float* __restrict__ kp,
             const bf16* __restrict__ vp,
             const bf16* __restrict__ Kbc, const bf16* __restrict__ Vbc,
             const bf16* __restrict__ Skc, const bf16* __restrict__ Sbc,
             bf16* __restrict__ atn) {
    const int pos = ((blockIdx.x & 7) << 8) | (blockIdx.x >> 3);  // XCD-contiguous
    const int b = pos >> 10, l = pos & 1023;
    const int t = threadIdx.x;
    __shared__ float qs[640];
    __shared__ float sc5[5 * 32];
    __shared__ float sc14[14 * 32];
    __shared__ float w14T[32 * 14];   // transposed: [tap][head]

    if (t < 160) ((float4*)qs)[t] = ((const float4*)(qp + (size_t)pos * 640))[t];
    __syncthreads();

    // Phase A: score[s][j] = q[s].kwin[s][j]; 8 lanes/dot, stride-32 interleave
    {
        const int j = t >> 3, p = t & 7;
#pragma unroll
        for (int s = 0; s < 5; ++s) {
            const int dil = (s < 2) ? 1 : (1 << (s - 1));
            const int pl = (31 * dil) >> 1;
            const int row = l + j * dil - pl;
            const float* q = qs + s * 128 + p * 4;
            float acc = 0.f;
            if (row >= 0 && row < 1024) {
                const float* kr = kp + (size_t)((b << 10) | row) * 640 + s * 128 + p * 4;
#pragma unroll
                for (int g = 0; g < 4; ++g) {
                    float4 kv = *(const float4*)(kr + g * 32);
                    float4 qv = *(const float4*)(q + g * 32);
                    acc += qv.x * kv.x + qv.y * kv.y + qv.z * kv.z + qv.w * kv.w;
                }
            } else {
                const bf16* kb = Kbc + s * 128 + p * 4;   // pad rows project the bias
#pragma unroll
                for (int g = 0; g < 4; ++g) {
                    float4 qv = *(const float4*)(q + g * 32);
                    acc += qv.x * (float)kb[g * 32] + qv.y * (float)kb[g * 32 + 1]
                         + qv.z * (float)kb[g * 32 + 2] + qv.w * (float)kb[g * 32 + 3];
                }
            }
            acc += __shfl_xor(acc, 1);
            acc += __shfl_xor(acc, 2);
            acc += __shfl_xor(acc, 4);
            if (p == 0) sc5[s * 32 + j] = acc;
        }
    }
    __syncthreads();

    // Phase B: supersample + positional resampling (448 outputs), vectorized Sk
    for (int idx = t; idx < 448; idx += 256) {
        const int h = idx >> 5;
        const int s = (h < 5) ? 0 : (h < 10) ? 1 : (h < 12) ? 2 : (h == 12) ? 3 : 4;
        const s16x8* sk = (const s16x8*)((const short*)Skc + idx * 32);
        const float* sc = sc5 + s * 32;
        float acc = b2f(((const short*)Sbc)[idx]);
#pragma unroll
        for (int g = 0; g < 4; ++g) {
            s16x8 kk = sk[g];
#pragma unroll
            for (int r = 0; r < 8; ++r) acc += sc[g * 8 + r] * b2f(kk[r]);
        }
        sc14[idx] = acc;
    }
    __syncthreads();

    // Phase C: softmax, 16 lanes/head (2 taps each), shuffle-reduce width 16
    if (t < 224) {
        const int h = t >> 4, u = t & 15;
        float s0 = sc14[h * 32 + u], s1 = sc14[h * 32 + u + 16];
        float mx = fmaxf(s0, s1);
#pragma unroll
        for (int m = 1; m < 16; m <<= 1) mx = fmaxf(mx, __shfl_xor(mx, m));
        float e0 = __expf(s0 - mx), e1 = __expf(s1 - mx);
        float sum = e0 + e1;
#pragma unroll
        for (int m = 1; m < 16; m <<= 1) sum += __shfl_xor(sum, m);
        float inv = 1.f / sum;
        w14T[u * 14 + h] = e0 * inv;
        w14T[(u + 16) * 14 + h] = e1 * inv;
    }
    __syncthreads();

    // Phase D: attn[h][d8] = sum_j w[j][h] * vwin[h][j][d8]
    if (t < 224) {
        const int h = t >> 4, d8 = (t & 15) * 8;
        const int dil = (h < 10) ? 1 : (h < 12) ? 2 : (h == 12) ? 4 : 8;
        const int pl = (31 * dil) >> 1;
        const int col = h * 128 + d8;
        float acc[8] = {};
#pragma unroll
        for (int j = 0; j < 32; ++j) {
            const int row = l + j * dil - pl;
            const short* src = (row >= 0 && row < 1024)
                ? (const short*)vp + (size_t)((b << 10) | row) * 1792 + col
                : (const short*)Vbc + col;     // pad rows project the bias
            s16x8 v8 = *(const s16x8*)src;
            const float w = w14T[j * 14 + h];
#pragma unroll
            for (int r = 0; r < 8; ++r) acc[r] += w * b2f(v8[r]);
        }
        union { uint4 u; short h16[8]; } o;
#pragma unroll
        for (int r = 0; r < 8; ++r) o.h16[r] = f2b(acc[r]);
        *(uint4*)((short*)atn + (size_t)pos * 1792 + col) = o.u;
    }
}

extern "C" void kernel_launch(void* const* d_in, const int* in_sizes, int n_in,
                              void* d_out, int out_size, void* d_ws, size_t ws_size,
                              hipStream_t stream) {
    const int M = 2048;
    char* w = (char*)d_ws;
    size_t off = 0;
    auto alloc = [&](size_t bytes) -> char* {
        off = (off + 255) & ~(size_t)255;
        char* p = w + off; off += bytes; return p;
    };
    bf16* Qkc = (bf16*)alloc(409600 * 2);
    bf16* Qbc = (bf16*)alloc(640 * 2);
    bf16* Kkc = (bf16*)alloc(409600 * 2);
    bf16* Kbc = (bf16*)alloc(640 * 2);
    bf16* Vkc = (bf16*)alloc(1146880 * 2);
    bf16* Vbc = (bf16*)alloc(1792 * 2);
    bf16* Skc = (bf16*)alloc(14336 * 2);
    bf16* Sbc = (bf16*)alloc(448 * 2);
    bf16* Ckc = (bf16*)alloc(1146880 * 2);
    bf16* Cbc = (bf16*)alloc(640 * 2);
    float* qp = (float*)alloc((size_t)M * 640 * 4);
    float* kp = (float*)alloc((size_t)M * 640 * 4);
    bf16*  vp = (bf16*)alloc((size_t)M * 1792 * 2);
    bf16*  atn = (bf16*)alloc((size_t)M * 1792 * 2);

    CvtArgs ca;
    bf16* dsts[10] = {Qkc, Qbc, Kkc, Kbc, Vkc, Vbc, Skc, Sbc, Ckc, Cbc};
    const int ns[10] = {409600, 640, 409600, 640, 1146880, 1792, 14336, 448, 1146880, 640};
    int cum = 0;
    for (int i = 0; i < 10; ++i) {
        ca.src[i] = (const float*)d_in[3 + i];
        ca.dst[i] = dsts[i];
        ca.n[i] = ns[i];
        ca.bb[i] = cum;
        cum += (ns[i] + 1023) / 1024;
    }
    ca.bb[10] = cum;

    dim3 blk(256);
    convert_kernel<<<dim3(cum), blk, 0, stream>>>(ca);
    proj_kernel<<<dim3(768), blk, 0, stream>>>(
        (const float*)d_in[0], (const float*)d_in[1], (const float*)d_in[2],
        Qkc, Kkc, Vkc, Qbc, Kbc, Vbc, qp, kp, vp);
    attn_v4<<<dim3(2048), blk, 0, stream>>>(qp, kp, vp, Kbc, Vbc, Skc, Sbc, atn);
    collapse_kernel<<<dim3(320), blk, 0, stream>>>(atn, Ckc, Cbc, (float*)d_out);
}